// Round 10
// baseline (604.976 us; speedup 1.0000x reference)
//
#include <hip/hip_runtime.h>

#define HID   15
#define TMAIN 1024
#define FUT   64
#define OUTW  (TMAIN + FUT)   // 1088

typedef _Float16 v2h   __attribute__((ext_vector_type(2)));
typedef _Float16 v8h   __attribute__((ext_vector_type(8)));
typedef float    f32x4 __attribute__((ext_vector_type(4)));
typedef int      i32x4 __attribute__((ext_vector_type(4)));

__device__ __forceinline__ float rcp_(float x)  { return __builtin_amdgcn_rcpf(x); }
__device__ __forceinline__ float exp2_(float x) { return __builtin_amdgcn_exp2f(x); }

template<int I> struct ic { static constexpr int v = I; };
template<int J, int N, class F>
__device__ __forceinline__ void unroll_for(F&& f) {
    if constexpr (J < N) { f(ic<J>{}); unroll_for<J + 1, N>(f); }
}

// ds_swizzle BitMode: dest i reads lane ((i&and)|or)^xor within 32-lane halves.
template<int PAT>
__device__ __forceinline__ int swzi(int x) { return __builtin_amdgcn_ds_swizzle(x, PAT); }
template<int PAT>
__device__ __forceinline__ float swzf(float x) { return __int_as_float(swzi<PAT>(__float_as_int(x))); }

__device__ __forceinline__ int bpermi(int addr, int x) { return __builtin_amdgcn_ds_bpermute(addr, x); }
__device__ __forceinline__ float bpermf(int addr, float x) { return __int_as_float(bpermi(addr, __float_as_int(x))); }

// DPP: row_shl:n = 0x100+n, row_shr:n = 0x110+n (16-lane rows, bound_ctrl 0-fill)
template<int CTRL>
__device__ __forceinline__ int dppi(int x) {
    return __builtin_amdgcn_update_dpp(0, x, CTRL, 0xF, 0xF, true);
}

__device__ __forceinline__ v2h pkrtz(float lo, float hi) {
    return __builtin_bit_cast(v2h, __builtin_amdgcn_cvt_pkrtz(lo, hi));
}
__device__ __forceinline__ f32x4 mfma16(v8h a, v8h b, f32x4 c) {
    return __builtin_amdgcn_mfma_f32_16x16x32_f16(a, b, c, 0, 0, 0);
}
template<int I>
__device__ __forceinline__ float xel(const f32x4& a, const f32x4& b) {
    if constexpr (I < 4) return a[I]; else return b[I - 4];
}

// R17 = R16 (verified zero-DS loop + joint-rcp acts) at 2 samples/wave ->
// 2048 waves -> 2 waves/SIMD.  R16 PMC: 30% stall at 1 wave/SIMD (the
// MFMA->gsel->exp2->rcp->exp2->rcp->pack serial chain has no TLP cover).
// Per-wave op count is unchanged (wave-wide ops), so 2/SIMD should overlap
// the two waves' stalls: wall/step ~790 -> ~555+e cyc.  Trans-pipe fits:
// 2 x 224 < 555.
//  Layout: col = 2j+s (s = c&1 sample parity, j = c>>1 replica); unit =
//  4u+(j&3).  Parity-safe rotations ror2/4/6 (even shifts) replace ror4/8/12;
//  verified mux tree applies with cg->j&3.  Stash: u3 lanes own 8 j-slots
//  per sample -> single oA reg.  Future butterfly adds parity-safe xor2.
//  A/C fragments, W_lin row-15 hijack, x-slot k15, pipeline: unchanged.
__global__ __launch_bounds__(256)
__attribute__((amdgpu_waves_per_eu(2, 2)))
void lstm_seq_kernel(const float* __restrict__ input,
                     const float* __restrict__ W_ih1, const float* __restrict__ W_hh1,
                     const float* __restrict__ b_ih1, const float* __restrict__ b_hh1,
                     const float* __restrict__ W_ih2, const float* __restrict__ W_hh2,
                     const float* __restrict__ b_ih2, const float* __restrict__ b_hh2,
                     const float* __restrict__ W_lin, const float* __restrict__ b_lin,
                     float* __restrict__ out)
{
    const int tid  = threadIdx.x;
    const int wq   = tid >> 6;
    const int lane = tid & 63;
    const int u    = lane >> 4;        // K-block row / D row-group
    const int c    = lane & 15;        // MFMA col (B/D) and A-row
    const int s    = c & 1;            // sample parity
    const int j    = c >> 1;           // replica index 0..7
    const int b0   = (blockIdx.x * 4 + wq) * 2;    // 2 samples per wave

    const float L2E = 1.442695040888963f;
    const float sA[4] = {-L2E, -L2E, -2.0f * L2E, -L2E};
    const float blin = b_lin[0];

    // ---- static A fragments (chunk = gate, rows = units) + bias C ----
    v8h   A1[4], A2[4];
    f32x4 C1[4], C2[4];
    #pragma unroll
    for (int m = 0; m < 4; ++m) {
        #pragma unroll
        for (int e = 0; e < 8; ++e) {
            const int k = (e < 4) ? (4 * u + e) : (16 + 4 * u + (e - 4));
            float v1 = 0.0f, v2 = 0.0f;
            if (c < HID) {
                const int wr = m * HID + c;            // gate m, unit c
                if (k < HID)       { v1 = W_hh1[wr * HID + k]; v2 = W_ih2[wr * HID + k]; }
                else if (k == HID) { v1 = W_ih1[wr]; }                     // x slot
                else if (k >= 16 && k < 16 + HID) { v2 = W_hh2[wr * HID + (k - 16)]; }
            }
            float a2v = sA[m] * v2;
            if (c == 15 && m == 3 && k >= 16 && k < 16 + HID)
                a2v = W_lin[k - 16];                   // out-row (unscaled)
            A1[m][e] = (_Float16)(sA[m] * v1);
            A2[m][e] = (_Float16)a2v;
        }
        #pragma unroll
        for (int r = 0; r < 4; ++r) {                  // D row 4u+r = unit 4u+r, gate m
            const int U = 4 * u + r;
            float bv1 = 0.0f, bv2 = 0.0f;
            if (U < HID) {
                bv1 = sA[m] * (b_ih1[m * HID + U] + b_hh1[m * HID + U]);
                bv2 = sA[m] * (b_ih2[m * HID + U] + b_hh2[m * HID + U]);
            }
            if (u == 3 && m == 3 && r == 3) bv2 = blin;   // out-row bias
            C1[m][r] = bv1; C2[m][r] = bv2;
        }
    }

    const int   Uown = 4 * u + (j & 3);                // owned unit
    // future-phase out-dot weight; kill the 2nd replica (j>=4) to avoid
    // double-count, and guard the pad unit 15.
    const float wl2  = (j < 4 && Uown < HID) ? W_lin[Uown] : 0.0f;

    const bool jb0   = (j & 1) != 0;
    const bool jb1   = (j & 2) != 0;
    const bool u3b   = (u == 3);
    const int  a32   = (lane ^ 32) << 2;

    int B0 = 0, B1 = 0, B2 = 0, B3 = 0;
    float c1v = 0.0f, c2v = 0.0f;
    float oA = 0.0f;

    auto makeB = [&]() -> v8h {
        return __builtin_bit_cast(v8h, (i32x4){B0, B1, B2, B3});
    };

    // P_m = q_m[j&3] (constant-index cndmask tree)
    auto gsel = [&](const f32x4& q0, const f32x4& q1, const f32x4& q2, const f32x4& q3,
                    float& g0, float& g1, float& g2, float& g3) {
        auto pick = [&](const f32x4& q) -> float {
            const float t0 = jb0 ? q[1] : q[0];
            const float t1 = jb0 ? q[3] : q[2];
            return jb1 ? t1 : t0;
        };
        g0 = pick(q0); g1 = pick(q1); g2 = pick(q2); g3 = pick(q3);
    };

    // joint-rcp LSTM cell update (verified R16).  Exact algebra:
    //  c' = [c*Di*Dg + (1-Eg)*Df] / (Di*Df*Dg)   (1 rcp)
    //  h  = (1-Y) / [(1+Y)*(1+Eo)],  Y = 2^(-2*c'*log2e)   (1 rcp)
    // pad unit 15: pre-acts 0 -> c stays 0 -> h exactly 0 (ov-hijack safe).
    auto acts = [&](float g0, float g1, float g2, float g3, float& cv) -> float {
        const float Ei = exp2_(g0);
        const float Ef = exp2_(g1);
        const float Eg = exp2_(g2);
        const float Eo = exp2_(g3);
        const float Di = 1.0f + Ei;
        const float Df = 1.0f + Ef;
        const float Dg = 1.0f + Eg;
        const float P  = Di * Dg;
        const float t  = __builtin_fmaf(-Eg, Df, Df);          // (1-Eg)*Df
        const float numer = __builtin_fmaf(cv, P, t);
        cv = numer * rcp_(P * Df);
        const float Y  = exp2_(cv * -2.885390081777927f);
        return (1.0f - Y) * rcp_((1.0f + Y) * (1.0f + Eo));
    };

    // slots: s_e = h of unit 4u+e, own sample.  Parity-safe even rotations:
    // R[t] = ror(2t) holds h[4u+((j-t)&3)]  =>  s_e = R[(j-e)&3].
    // Same verified tree as R15/R16 with cg->j&3, r4/r8/r12 -> r2/r4/r6.
    auto slots = [&](float h, float& s0, float& s1, float& s2, float& s3) {
        const int hb = __float_as_int(h);
        const float r2 = __int_as_float(dppi<0x112>(hb) | dppi<0x10E>(hb)); // ror2
        const float r4 = __int_as_float(dppi<0x114>(hb) | dppi<0x10C>(hb)); // ror4
        const float r6 = __int_as_float(dppi<0x116>(hb) | dppi<0x10A>(hb)); // ror6
        const float A0 = jb0 ? r2 : h;
        const float A1 = jb0 ? r6 : r4;
        const float A2 = jb0 ? h  : r6;
        const float A3 = jb0 ? r4 : r2;
        s0 = jb1 ? A1 : A0;
        s1 = jb1 ? A3 : A2;
        s2 = jb1 ? A0 : A1;
        s3 = jb1 ? A2 : A3;
    };

    auto pack01 = [&](float h1n, float xv) {           // B regs 0,1 <- h1 (+x at u3)
        float s0, s1, s2, s3; slots(h1n, s0, s1, s2, s3);
        B0 = __builtin_bit_cast(int, pkrtz(s0, s1));
        B1 = __builtin_bit_cast(int, pkrtz(s2, u3b ? xv : s3));
    };
    auto pack23 = [&](float h2n) {                     // B regs 2,3 <- h2
        float s0, s1, s2, s3; slots(h2n, s0, s1, s2, s3);
        B2 = __builtin_bit_cast(int, pkrtz(s0, s1));
        B3 = __builtin_bit_cast(int, pkrtz(s2, s3));
    };

    auto stash = [&](auto SigC, float ov) {            // slot sig owned by j==sig
        constexpr int SIG = decltype(SigC)::v;
        oA = (j == SIG) ? ov : oA;
    };

    const size_t xadr   = (size_t)(b0 + s) * TMAIN;
    const size_t outb_o = (size_t)(b0 + s) * OUTW;

    auto storeChunk = [&](int chIdx, int baseOff) {
        if (u3b) out[outb_o + baseOff + (size_t)chIdx * 8 + j] = oA;
    };

    // out = sum over the 32 same-parity lanes (each unit 2x, wl2 zeroed on
    // the j>=4 copy).  Parity-safe xor chain.  Future/epilogue only.
    auto outdot = [&](float h) -> float {
        float pv = wl2 * h;
        pv += swzf<0x081F>(pv);                        // xor 2
        pv += swzf<0x101F>(pv);                        // xor 4
        pv += swzf<0x201F>(pv);                        // xor 8
        pv += swzf<0x401F>(pv);                        // xor 16
        pv += bpermf(a32, pv);                         // xor 32
        return pv + blin;
    };

    // pipelined iteration t: B = {h1(t), x(t+1), h2(t-1)}
    // -> h2(t), h1(t+1), ov(t-1) (=e3[3] on u3); builds B(t+1) with x(t+2)
    auto iterP = [&](auto Sc, float xv2) {
        constexpr int S = decltype(Sc)::v;
        const v8h Bv = makeB();
        f32x4 e0 = mfma16(A2[0], Bv, C2[0]);
        f32x4 e1 = mfma16(A2[1], Bv, C2[1]);
        f32x4 e2 = mfma16(A2[2], Bv, C2[2]);
        f32x4 e3 = mfma16(A2[3], Bv, C2[3]);
        f32x4 d0 = mfma16(A1[0], Bv, C1[0]);
        f32x4 d1 = mfma16(A1[1], Bv, C1[1]);
        f32x4 d2 = mfma16(A1[2], Bv, C1[2]);
        f32x4 d3 = mfma16(A1[3], Bv, C1[3]);

        stash(ic<(S + 7) & 7>{}, e3[3]);               // ov(t-1)

        float Q0, Q1, Q2, Q3, P0, P1, P2, P3;
        gsel(e0, e1, e2, e3, Q0, Q1, Q2, Q3);
        gsel(d0, d1, d2, d3, P0, P1, P2, P3);

        const float h2n = acts(Q0, Q1, Q2, Q3, c2v);   // h2(t)
        const float h1n = acts(P0, P1, P2, P3, c1v);   // h1(t+1)

        pack01(h1n, xv2);
        pack23(h2n);
    };

    // serial step (future): B = {h1(t-1), x(t)=ov(t-1), h2(t-1)}
    auto stepS = [&](auto Sc) {
        constexpr int S = decltype(Sc)::v;
        const v8h Bv = makeB();
        f32x4 d0 = mfma16(A1[0], Bv, C1[0]);
        f32x4 d1 = mfma16(A1[1], Bv, C1[1]);
        f32x4 d2 = mfma16(A1[2], Bv, C1[2]);
        f32x4 d3 = mfma16(A1[3], Bv, C1[3]);
        float P0, P1, P2, P3;
        gsel(d0, d1, d2, d3, P0, P1, P2, P3);
        const float h1n = acts(P0, P1, P2, P3, c1v);
        pack01(h1n, 0.0f);                             // x patched after ov known

        const v8h Bv2 = makeB();                       // {h1(t), -, h2(t-1)}
        f32x4 e0 = mfma16(A2[0], Bv2, C2[0]);
        f32x4 e1 = mfma16(A2[1], Bv2, C2[1]);
        f32x4 e2 = mfma16(A2[2], Bv2, C2[2]);
        f32x4 e3 = mfma16(A2[3], Bv2, C2[3]);
        float Q0, Q1, Q2, Q3;
        gsel(e0, e1, e2, e3, Q0, Q1, Q2, Q3);
        const float h2n = acts(Q0, Q1, Q2, Q3, c2v);

        const float ov = outdot(h2n);                  // ov(t), per-sample
        stash(ic<S>{}, ov);
        // patch x(t+1)=ov into B1.hi at u3
        const int xb = __builtin_bit_cast(int, pkrtz(0.0f, ov)) & 0xFFFF0000;
        B1 = u3b ? ((B1 & 0xFFFF) | xb) : B1;
        pack23(h2n);
    };

    // ---- prologue: h(-1)=0; h1(0); B(0) = {h1(0), x(1), 0} ----
    f32x4 xcA = *(const f32x4*)&input[xadr];
    f32x4 xcB = *(const f32x4*)&input[xadr + 4];
    {
        B0 = B2 = B3 = 0;
        B1 = u3b ? __builtin_bit_cast(int, pkrtz(0.0f, xcA[0])) : 0;  // x(0)
        const v8h Bv = makeB();
        f32x4 d0 = mfma16(A1[0], Bv, C1[0]);
        f32x4 d1 = mfma16(A1[1], Bv, C1[1]);
        f32x4 d2 = mfma16(A1[2], Bv, C1[2]);
        f32x4 d3 = mfma16(A1[3], Bv, C1[3]);
        float P0, P1, P2, P3;
        gsel(d0, d1, d2, d3, P0, P1, P2, P3);
        const float h1n = acts(P0, P1, P2, P3, c1v);
        pack01(h1n, xcA[1]);                           // x(1)
        B2 = B3 = 0;                                   // h2(-1) = 0
    }

    // ---- main: 127 full chunks of 8 pipelined iters (t = 0..1015) ----
    #pragma unroll 1
    for (int ch = 0; ch < 127; ++ch) {
        const f32x4 xnA = *(const f32x4*)&input[xadr + (size_t)(ch + 1) * 8];
        const f32x4 xnB = *(const f32x4*)&input[xadr + (size_t)(ch + 1) * 8 + 4];
        iterP(ic<0>{}, xel<2>(xcA, xcB));
        if (ch > 0) storeChunk(ch - 1, 0);
        iterP(ic<1>{}, xel<3>(xcA, xcB));
        iterP(ic<2>{}, xel<4>(xcA, xcB));
        iterP(ic<3>{}, xel<5>(xcA, xcB));
        iterP(ic<4>{}, xel<6>(xcA, xcB));
        iterP(ic<5>{}, xel<7>(xcA, xcB));
        iterP(ic<6>{}, xnA[0]);
        iterP(ic<7>{}, xnA[1]);
        xcA = xnA; xcB = xnB;
    }

    // ---- final chunk (t = 1016..1022) + L2-only epilogue (h2(1023)) ----
    {
        iterP(ic<0>{}, xel<2>(xcA, xcB));
        storeChunk(126, 0);
        iterP(ic<1>{}, xel<3>(xcA, xcB));
        iterP(ic<2>{}, xel<4>(xcA, xcB));
        iterP(ic<3>{}, xel<5>(xcA, xcB));
        iterP(ic<4>{}, xel<6>(xcA, xcB));
        iterP(ic<5>{}, xel<7>(xcA, xcB));
        iterP(ic<6>{}, 0.0f);                          // x(1024) patched below

        // epilogue: B(1023) = {h1(1023), -, h2(1022)}
        const v8h Bv = makeB();
        f32x4 e0 = mfma16(A2[0], Bv, C2[0]);
        f32x4 e1 = mfma16(A2[1], Bv, C2[1]);
        f32x4 e2 = mfma16(A2[2], Bv, C2[2]);
        f32x4 e3 = mfma16(A2[3], Bv, C2[3]);
        stash(ic<6>{}, e3[3]);                         // ov(1022)
        float Q0, Q1, Q2, Q3;
        gsel(e0, e1, e2, e3, Q0, Q1, Q2, Q3);
        const float h2n = acts(Q0, Q1, Q2, Q3, c2v);
        const float ov23 = outdot(h2n);                // ov(1023)
        stash(ic<7>{}, ov23);
        storeChunk(127, 0);
        // B(1024): keep regs0,1 (h1(1023)); x(1024)=ov(1023); regs2,3 <- h2(1023)
        const int xb = __builtin_bit_cast(int, pkrtz(0.0f, ov23)) & 0xFFFF0000;
        B1 = u3b ? ((B1 & 0xFFFF) | xb) : B1;
        pack23(h2n);
    }

    // ---- future: 64 serial steps, x = previous out ----
    #pragma unroll 1
    for (int fc = 0; fc < FUT / 8; ++fc) {
        unroll_for<0, 8>([&](auto sc) { stepS(sc); });
        storeChunk(fc, TMAIN);
    }
}

extern "C" void kernel_launch(void* const* d_in, const int* in_sizes, int n_in,
                              void* d_out, int out_size, void* d_ws, size_t ws_size,
                              hipStream_t stream)
{
    const float* input = (const float*)d_in[0];
    const float* W_ih1 = (const float*)d_in[1];
    const float* W_hh1 = (const float*)d_in[2];
    const float* b_ih1 = (const float*)d_in[3];
    const float* b_hh1 = (const float*)d_in[4];
    const float* W_ih2 = (const float*)d_in[5];
    const float* W_hh2 = (const float*)d_in[6];
    const float* b_ih2 = (const float*)d_in[7];
    const float* b_hh2 = (const float*)d_in[8];
    const float* W_lin = (const float*)d_in[9];
    const float* b_lin = (const float*)d_in[10];
    // d_in[11] = future (=64), compiled in as FUT

    // 4096 batches / (2 per wave * 4 waves per block) = 512 blocks
    // -> 2048 waves = 2 waves/SIMD (TLP to cover the serial act chain)
    lstm_seq_kernel<<<512, 256, 0, stream>>>(
        input, W_ih1, W_hh1, b_ih1, b_hh1,
        W_ih2, W_hh2, b_ih2, b_hh2, W_lin, b_lin,
        (float*)d_out);
}

// Round 13
// 426.342 us; speedup vs baseline: 1.4190x; 1.4190x over previous
//
#include <hip/hip_runtime.h>

#define HID   15
#define TMAIN 1024
#define FUT   64
#define OUTW  (TMAIN + FUT)   // 1088

typedef _Float16 v2h   __attribute__((ext_vector_type(2)));
typedef _Float16 v8h   __attribute__((ext_vector_type(8)));
typedef float    f32x4 __attribute__((ext_vector_type(4)));
typedef int      i32x4 __attribute__((ext_vector_type(4)));

__device__ __forceinline__ float rcp_(float x)  { return __builtin_amdgcn_rcpf(x); }
__device__ __forceinline__ float exp2_(float x) { return __builtin_amdgcn_exp2f(x); }

template<int I> struct ic { static constexpr int v = I; };
template<int J, int N, class F>
__device__ __forceinline__ void unroll_for(F&& f) {
    if constexpr (J < N) { f(ic<J>{}); unroll_for<J + 1, N>(f); }
}

// ds_swizzle BitMode: dest i reads lane ((i&and)|or)^xor within 32-lane halves.
// offset = (xor<<10)|(or<<5)|and
template<int PAT>
__device__ __forceinline__ int swzi(int x) { return __builtin_amdgcn_ds_swizzle(x, PAT); }
template<int PAT>
__device__ __forceinline__ float swzf(float x) { return __int_as_float(swzi<PAT>(__float_as_int(x))); }

__device__ __forceinline__ int bpermi(int addr, int x) { return __builtin_amdgcn_ds_bpermute(addr, x); }
__device__ __forceinline__ float bpermf(int addr, float x) { return __int_as_float(bpermi(addr, __float_as_int(x))); }

// DPP: row_shl:n = 0x100+n, row_shr:n = 0x110+n (16-lane rows, bound_ctrl 0-fill)
template<int CTRL>
__device__ __forceinline__ int dppi(int x) {
    return __builtin_amdgcn_update_dpp(0, x, CTRL, 0xF, 0xF, true);
}

__device__ __forceinline__ v2h pkrtz(float lo, float hi) {
    return __builtin_bit_cast(v2h, __builtin_amdgcn_cvt_pkrtz(lo, hi));
}
__device__ __forceinline__ f32x4 mfma16(v8h a, v8h b, f32x4 c) {
    return __builtin_amdgcn_mfma_f32_16x16x32_f16(a, b, c, 0, 0, 0);
}
template<int I>
__device__ __forceinline__ float xel(const f32x4& a, const f32x4& b) {
    if constexpr (I < 4) return a[I]; else return b[I - 4];
}

// R18 = R16 (verified: zero-DS-bpermute loop, joint-rcp acts, 4 samples/wave
// = 1024 waves) + swizzle-broadcast B-pack.
// R17 post-mortem: 2 samples/wave doubled TOTAL issue work (2048 waves x
// unchanged per-wave ops) -- TLP covers 30% stall, not +100% work.  Occupancy
// path closed; back to the 4-sample layout.
// Pack change: old slots tree (9 dpp/or + 8 cndmask + 2 pkrtz per h, ~38 ops
// per step) -> p = pkrtz(h, shl4(h)) puts pair {h[4u+2q], h[4u+2q+1]} at col
// 4q+s; one ds_swizzle per B-reg broadcasts col {s | 8+s} across the row
// (lane = (i&0x13)|{0,8}).  Per h: 1 dpp + 1 pkrtz + 2 swz (+x-patch at u3).
// ~-54 issue cyc/step.  All else identical to R16.
__global__ __launch_bounds__(256)
__attribute__((amdgpu_waves_per_eu(1, 1)))
void lstm_seq_kernel(const float* __restrict__ input,
                     const float* __restrict__ W_ih1, const float* __restrict__ W_hh1,
                     const float* __restrict__ b_ih1, const float* __restrict__ b_hh1,
                     const float* __restrict__ W_ih2, const float* __restrict__ W_hh2,
                     const float* __restrict__ b_ih2, const float* __restrict__ b_hh2,
                     const float* __restrict__ W_lin, const float* __restrict__ b_lin,
                     float* __restrict__ out)
{
    const int tid  = threadIdx.x;
    const int wq   = tid >> 6;
    const int lane = tid & 63;
    const int u    = lane >> 4;        // K-block row / D row-group
    const int c    = lane & 15;        // MFMA col (B/D) and A-row
    const int s    = c & 3;            // sample within wave
    const int cg   = c >> 2;           // col-group == owned-unit offset
    const int b0   = (blockIdx.x * 4 + wq) * 4;

    const float L2E = 1.442695040888963f;
    const float sA[4] = {-L2E, -L2E, -2.0f * L2E, -L2E};
    const float blin = b_lin[0];

    // ---- static A fragments (chunk = gate, rows = units) + bias C ----
    v8h   A1[4], A2[4];
    f32x4 C1[4], C2[4];
    #pragma unroll
    for (int m = 0; m < 4; ++m) {
        #pragma unroll
        for (int e = 0; e < 8; ++e) {
            const int k = (e < 4) ? (4 * u + e) : (16 + 4 * u + (e - 4));
            float v1 = 0.0f, v2 = 0.0f;
            if (c < HID) {
                const int wr = m * HID + c;            // gate m, unit c
                if (k < HID)       { v1 = W_hh1[wr * HID + k]; v2 = W_ih2[wr * HID + k]; }
                else if (k == HID) { v1 = W_ih1[wr]; }                     // x slot
                else if (k >= 16 && k < 16 + HID) { v2 = W_hh2[wr * HID + (k - 16)]; }
            }
            float a2v = sA[m] * v2;
            if (c == 15 && m == 3 && k >= 16 && k < 16 + HID)
                a2v = W_lin[k - 16];                   // out-row (unscaled)
            A1[m][e] = (_Float16)(sA[m] * v1);
            A2[m][e] = (_Float16)a2v;
        }
        #pragma unroll
        for (int r = 0; r < 4; ++r) {                  // D row 4u+r = unit 4u+r, gate m
            const int U = 4 * u + r;
            float bv1 = 0.0f, bv2 = 0.0f;
            if (U < HID) {
                bv1 = sA[m] * (b_ih1[m * HID + U] + b_hh1[m * HID + U]);
                bv2 = sA[m] * (b_ih2[m * HID + U] + b_hh2[m * HID + U]);
            }
            if (u == 3 && m == 3 && r == 3) bv2 = blin;   // out-row bias
            C1[m][r] = bv1; C2[m][r] = bv2;
        }
    }

    const int   Uown = 4 * u + cg;                     // owned unit
    const float wl2  = (Uown < HID) ? W_lin[Uown] : 0.0f;

    const bool cgb0  = (cg & 1) != 0;
    const bool cgb1  = (cg & 2) != 0;
    const bool u3b   = (u == 3);
    const int  a32   = (lane ^ 32) << 2;

    int B0 = 0, B1 = 0, B2 = 0, B3 = 0;
    float c1v = 0.0f, c2v = 0.0f;
    float oA = 0.0f, oB = 0.0f;

    auto makeB = [&]() -> v8h {
        return __builtin_bit_cast(v8h, (i32x4){B0, B1, B2, B3});
    };

    // P_m = q_m[cg] (constant-index cndmask tree)
    auto gsel = [&](const f32x4& q0, const f32x4& q1, const f32x4& q2, const f32x4& q3,
                    float& g0, float& g1, float& g2, float& g3) {
        auto pick = [&](const f32x4& q) -> float {
            const float t0 = cgb0 ? q[1] : q[0];
            const float t1 = cgb0 ? q[3] : q[2];
            return cgb1 ? t1 : t0;
        };
        g0 = pick(q0); g1 = pick(q1); g2 = pick(q2); g3 = pick(q3);
    };

    // joint-rcp LSTM cell update (verified R16).  Exact algebra:
    //  c' = [c*Di*Dg + (1-Eg)*Df] / (Di*Df*Dg)   (1 rcp)
    //  h  = (1-Y) / [(1+Y)*(1+Eo)],  Y = 2^(-2*c'*log2e)   (1 rcp)
    // pad unit 15: pre-acts 0 -> c stays 0 -> h exactly 0 (ov-hijack safe).
    auto acts = [&](float g0, float g1, float g2, float g3, float& cv) -> float {
        const float Ei = exp2_(g0);
        const float Ef = exp2_(g1);
        const float Eg = exp2_(g2);
        const float Eo = exp2_(g3);
        const float Di = 1.0f + Ei;
        const float Df = 1.0f + Ef;
        const float Dg = 1.0f + Eg;
        const float P  = Di * Dg;
        const float t  = __builtin_fmaf(-Eg, Df, Df);          // (1-Eg)*Df
        const float numer = __builtin_fmaf(cv, P, t);
        cv = numer * rcp_(P * Df);
        const float Y  = exp2_(cv * -2.885390081777927f);
        return (1.0f - Y) * rcp_((1.0f + Y) * (1.0f + Eo));
    };

    // B-pack via pair + swizzle-broadcast:
    //  p = pkrtz(h, shl4(h)): col 4q+s holds pair {h[4u+2q'], ...} -- cols
    //  s (cg=0) -> {h[4u],h[4u+1]}, 8+s (cg=2) -> {h[4u+2],h[4u+3]}.
    //  swz and=0x13 keeps row-bit4 + sample bits -> broadcast col {s|8+s}
    //  across the 16-lane row.  (bit5 / upper half handled per-32 by HW.)
    auto pack01 = [&](float h1n, float xv) {           // B regs 0,1 <- h1 (+x at u3)
        const int hb = __float_as_int(h1n);
        const float hr = __int_as_float(dppi<0x104>(hb));      // col+4, 0-fill
        const int p = __builtin_bit_cast(int, pkrtz(h1n, hr));
        B0 = swzi<0x0013>(p);                          // (i&0x13)|0  -> col s
        B1 = swzi<0x0113>(p);                          // (i&0x13)|8  -> col 8+s
        const int xb = __builtin_bit_cast(int, pkrtz(0.0f, xv)) & 0xFFFF0000;
        B1 = u3b ? ((B1 & 0xFFFF) | xb) : B1;          // x rides B1.hi at u3
    };
    auto pack23 = [&](float h2n) {                     // B regs 2,3 <- h2
        const int hb = __float_as_int(h2n);
        const float hr = __int_as_float(dppi<0x104>(hb));
        const int p = __builtin_bit_cast(int, pkrtz(h2n, hr));
        B2 = swzi<0x0013>(p);
        B3 = swzi<0x0113>(p);
    };

    auto stash = [&](auto SigC, float ov) {            // slot sig -> oA/oB at cg==sig&3
        constexpr int SIG = decltype(SigC)::v;
        const bool own = (cg == (SIG & 3));
        if constexpr (SIG < 4) oA = own ? ov : oA;
        else                   oB = own ? ov : oB;
    };

    const size_t xadr   = (size_t)(b0 + s) * TMAIN;
    const size_t outb_o = (size_t)(b0 + s) * OUTW;

    auto storeChunk = [&](int chIdx, int baseOff) {
        if (u3b) {
            out[outb_o + baseOff + (size_t)chIdx * 8 + cg]     = oA;
            out[outb_o + baseOff + (size_t)chIdx * 8 + 4 + cg] = oB;
        }
    };

    // out = sum over 16 unit-lanes of this sample (verified chain)
    auto outdot = [&](float h) -> float {
        float pv = wl2 * h;
        pv += swzf<0x101F>(pv);                        // xor 4  (cg bit0)
        pv += swzf<0x201F>(pv);                        // xor 8  (cg bit1)
        pv += swzf<0x401F>(pv);                        // xor 16 (u bit0)
        pv += bpermf(a32, pv);                         // xor 32 (u bit1)
        return pv + blin;
    };

    // pipelined iteration t: B = {h1(t), x(t+1), h2(t-1)}
    // -> h2(t), h1(t+1), ov(t-1) (=e3[3]); builds B(t+1) with x(t+2)=xv2
    auto iterP = [&](auto Sc, float xv2) {
        constexpr int S = decltype(Sc)::v;
        const v8h Bv = makeB();
        f32x4 e0 = mfma16(A2[0], Bv, C2[0]);
        f32x4 e1 = mfma16(A2[1], Bv, C2[1]);
        f32x4 e2 = mfma16(A2[2], Bv, C2[2]);
        f32x4 e3 = mfma16(A2[3], Bv, C2[3]);
        f32x4 d0 = mfma16(A1[0], Bv, C1[0]);
        f32x4 d1 = mfma16(A1[1], Bv, C1[1]);
        f32x4 d2 = mfma16(A1[2], Bv, C1[2]);
        f32x4 d3 = mfma16(A1[3], Bv, C1[3]);

        stash(ic<(S + 7) & 7>{}, e3[3]);               // ov(t-1)

        float Q0, Q1, Q2, Q3, P0, P1, P2, P3;
        gsel(e0, e1, e2, e3, Q0, Q1, Q2, Q3);
        gsel(d0, d1, d2, d3, P0, P1, P2, P3);

        const float h2n = acts(Q0, Q1, Q2, Q3, c2v);   // h2(t)   (pad: exact 0)
        const float h1n = acts(P0, P1, P2, P3, c1v);   // h1(t+1) (pad: exact 0)

        pack01(h1n, xv2);
        pack23(h2n);
    };

    // serial step (future): B = {h1(t-1), x(t)=ov(t-1), h2(t-1)}
    auto stepS = [&](auto Sc) {
        constexpr int S = decltype(Sc)::v;
        const v8h Bv = makeB();
        f32x4 d0 = mfma16(A1[0], Bv, C1[0]);
        f32x4 d1 = mfma16(A1[1], Bv, C1[1]);
        f32x4 d2 = mfma16(A1[2], Bv, C1[2]);
        f32x4 d3 = mfma16(A1[3], Bv, C1[3]);
        float P0, P1, P2, P3;
        gsel(d0, d1, d2, d3, P0, P1, P2, P3);
        const float h1n = acts(P0, P1, P2, P3, c1v);
        pack01(h1n, 0.0f);                             // x patched after ov known

        const v8h Bv2 = makeB();                       // {h1(t), -, h2(t-1)}
        f32x4 e0 = mfma16(A2[0], Bv2, C2[0]);
        f32x4 e1 = mfma16(A2[1], Bv2, C2[1]);
        f32x4 e2 = mfma16(A2[2], Bv2, C2[2]);
        f32x4 e3 = mfma16(A2[3], Bv2, C2[3]);
        float Q0, Q1, Q2, Q3;
        gsel(e0, e1, e2, e3, Q0, Q1, Q2, Q3);
        const float h2n = acts(Q0, Q1, Q2, Q3, c2v);

        const float ov = outdot(h2n);                  // ov(t)
        stash(ic<S>{}, ov);
        // patch x(t+1)=ov into B1.hi at u3
        const int xb = __builtin_bit_cast(int, pkrtz(0.0f, ov)) & 0xFFFF0000;
        B1 = u3b ? ((B1 & 0xFFFF) | xb) : B1;
        pack23(h2n);
    };

    // ---- prologue: h(-1)=0; h1(0); B(0) = {h1(0), x(1), 0} ----
    f32x4 xcA = *(const f32x4*)&input[xadr];
    f32x4 xcB = *(const f32x4*)&input[xadr + 4];
    {
        B0 = B2 = B3 = 0;
        B1 = u3b ? __builtin_bit_cast(int, pkrtz(0.0f, xcA[0])) : 0;  // x(0)
        const v8h Bv = makeB();
        f32x4 d0 = mfma16(A1[0], Bv, C1[0]);
        f32x4 d1 = mfma16(A1[1], Bv, C1[1]);
        f32x4 d2 = mfma16(A1[2], Bv, C1[2]);
        f32x4 d3 = mfma16(A1[3], Bv, C1[3]);
        float P0, P1, P2, P3;
        gsel(d0, d1, d2, d3, P0, P1, P2, P3);
        const float h1n = acts(P0, P1, P2, P3, c1v);
        pack01(h1n, xcA[1]);                           // x(1)
        B2 = B3 = 0;                                   // h2(-1) = 0
    }

    // ---- main: 127 full chunks of 8 pipelined iters (t = 0..1015) ----
    #pragma unroll 1
    for (int ch = 0; ch < 127; ++ch) {
        const f32x4 xnA = *(const f32x4*)&input[xadr + (size_t)(ch + 1) * 8];
        const f32x4 xnB = *(const f32x4*)&input[xadr + (size_t)(ch + 1) * 8 + 4];
        iterP(ic<0>{}, xel<2>(xcA, xcB));
        if (ch > 0) storeChunk(ch - 1, 0);
        iterP(ic<1>{}, xel<3>(xcA, xcB));
        iterP(ic<2>{}, xel<4>(xcA, xcB));
        iterP(ic<3>{}, xel<5>(xcA, xcB));
        iterP(ic<4>{}, xel<6>(xcA, xcB));
        iterP(ic<5>{}, xel<7>(xcA, xcB));
        iterP(ic<6>{}, xnA[0]);
        iterP(ic<7>{}, xnA[1]);
        xcA = xnA; xcB = xnB;
    }

    // ---- final chunk (t = 1016..1022) + L2-only epilogue (h2(1023)) ----
    {
        iterP(ic<0>{}, xel<2>(xcA, xcB));
        storeChunk(126, 0);
        iterP(ic<1>{}, xel<3>(xcA, xcB));
        iterP(ic<2>{}, xel<4>(xcA, xcB));
        iterP(ic<3>{}, xel<5>(xcA, xcB));
        iterP(ic<4>{}, xel<6>(xcA, xcB));
        iterP(ic<5>{}, xel<7>(xcA, xcB));
        iterP(ic<6>{}, 0.0f);                          // x(1024) patched below

        // epilogue: B(1023) = {h1(1023), -, h2(1022)}
        const v8h Bv = makeB();
        f32x4 e0 = mfma16(A2[0], Bv, C2[0]);
        f32x4 e1 = mfma16(A2[1], Bv, C2[1]);
        f32x4 e2 = mfma16(A2[2], Bv, C2[2]);
        f32x4 e3 = mfma16(A2[3], Bv, C2[3]);
        stash(ic<6>{}, e3[3]);                         // ov(1022)
        float Q0, Q1, Q2, Q3;
        gsel(e0, e1, e2, e3, Q0, Q1, Q2, Q3);
        const float h2n = acts(Q0, Q1, Q2, Q3, c2v);
        const float ov23 = outdot(h2n);                // ov(1023)
        stash(ic<7>{}, ov23);
        storeChunk(127, 0);
        // B(1024): keep regs0,1 (h1(1023)); x(1024)=ov(1023); regs2,3 <- h2(1023)
        const int xb = __builtin_bit_cast(int, pkrtz(0.0f, ov23)) & 0xFFFF0000;
        B1 = u3b ? ((B1 & 0xFFFF) | xb) : B1;
        pack23(h2n);
    }

    // ---- future: 64 serial steps, x = previous out ----
    #pragma unroll 1
    for (int fc = 0; fc < FUT / 8; ++fc) {
        unroll_for<0, 8>([&](auto sc) { stepS(sc); });
        storeChunk(fc, TMAIN);
    }
}

extern "C" void kernel_launch(void* const* d_in, const int* in_sizes, int n_in,
                              void* d_out, int out_size, void* d_ws, size_t ws_size,
                              hipStream_t stream)
{
    const float* input = (const float*)d_in[0];
    const float* W_ih1 = (const float*)d_in[1];
    const float* W_hh1 = (const float*)d_in[2];
    const float* b_ih1 = (const float*)d_in[3];
    const float* b_hh1 = (const float*)d_in[4];
    const float* W_ih2 = (const float*)d_in[5];
    const float* W_hh2 = (const float*)d_in[6];
    const float* b_ih2 = (const float*)d_in[7];
    const float* b_hh2 = (const float*)d_in[8];
    const float* W_lin = (const float*)d_in[9];
    const float* b_lin = (const float*)d_in[10];
    // d_in[11] = future (=64), compiled in as FUT

    // 4096 batches / (4 per wave * 4 waves per block) = 256 blocks
    // (1024 waves = 1/SIMD; R17 showed thinner waves double total issue)
    lstm_seq_kernel<<<256, 256, 0, stream>>>(
        input, W_ih1, W_hh1, b_ih1, b_hh1,
        W_ih2, W_hh2, b_ih2, b_hh2, W_lin, b_lin,
        (float*)d_out);
}

// Round 14
// 415.524 us; speedup vs baseline: 1.4559x; 1.0260x over previous
//
#include <hip/hip_runtime.h>

#define HID   15
#define TMAIN 1024
#define FUT   64
#define OUTW  (TMAIN + FUT)   // 1088

typedef _Float16 v2h   __attribute__((ext_vector_type(2)));
typedef _Float16 v8h   __attribute__((ext_vector_type(8)));
typedef float    f32x4 __attribute__((ext_vector_type(4)));
typedef int      i32x4 __attribute__((ext_vector_type(4)));

__device__ __forceinline__ float rcp_(float x)  { return __builtin_amdgcn_rcpf(x); }
__device__ __forceinline__ float exp2_(float x) { return __builtin_amdgcn_exp2f(x); }

template<int I> struct ic { static constexpr int v = I; };
template<int J, int N, class F>
__device__ __forceinline__ void unroll_for(F&& f) {
    if constexpr (J < N) { f(ic<J>{}); unroll_for<J + 1, N>(f); }
}

// ds_swizzle BitMode: dest i reads lane ((i&and)|or)^xor within 32-lane halves.
// offset = (xor<<10)|(or<<5)|and
template<int PAT>
__device__ __forceinline__ int swzi(int x) { return __builtin_amdgcn_ds_swizzle(x, PAT); }
template<int PAT>
__device__ __forceinline__ float swzf(float x) { return __int_as_float(swzi<PAT>(__float_as_int(x))); }

__device__ __forceinline__ int bpermi(int addr, int x) { return __builtin_amdgcn_ds_bpermute(addr, x); }
__device__ __forceinline__ float bpermf(int addr, float x) { return __int_as_float(bpermi(addr, __float_as_int(x))); }

// DPP: row_shl:n = 0x100+n, row_shr:n = 0x110+n (16-lane rows, bound_ctrl 0-fill)
template<int CTRL>
__device__ __forceinline__ int dppi(int x) {
    return __builtin_amdgcn_update_dpp(0, x, CTRL, 0xF, 0xF, true);
}

__device__ __forceinline__ v2h pkrtz(float lo, float hi) {
    return __builtin_bit_cast(v2h, __builtin_amdgcn_cvt_pkrtz(lo, hi));
}
__device__ __forceinline__ f32x4 mfma16(v8h a, v8h b, f32x4 c) {
    return __builtin_amdgcn_mfma_f32_16x16x32_f16(a, b, c, 0, 0, 0);
}
template<int I>
__device__ __forceinline__ float xel(const f32x4& a, const f32x4& b) {
    if constexpr (I < 4) return a[I]; else return b[I - 4];
}

// R19 = R18 + criticality-split pack + stale-B trick.
// R18 post-mortem: swizzle pack cut VALU issue (VALUBusy 70->58%) but the 4
// ds_swizzles sit on the L1 recurrence critical path (pack01 -> lgkmcnt ->
// next MFMAs) -- issue traded 1:1 for lgkm exposure; wall flat (harness
// 452->426 from clock, profiled 409->413).
// Fix:
//  (1) pack01 (L1-critical) -> VALU rotation tree (verified R16 slots):
//      lgkm-free.
//  (2) pack23 (h2, one step of slack) -> keeps R18 swizzle broadcast, into
//      FRESH regs B2f/B3f.
//  (3) stale-B: A1's k>=16 cols are ZERO, so L1 (d) MFMAs consume STALE
//      B2s/B3s (one step older, settled; 0 x finite = 0) -- no lgkm dep.
//      d-MFMAs issue FIRST; their issue covers e-MFMAs' lgkm wait.
//  L1 loop (the true recurrence) = VALU+MFMA only, zero DS waits.
__global__ __launch_bounds__(256)
__attribute__((amdgpu_waves_per_eu(1, 1)))
void lstm_seq_kernel(const float* __restrict__ input,
                     const float* __restrict__ W_ih1, const float* __restrict__ W_hh1,
                     const float* __restrict__ b_ih1, const float* __restrict__ b_hh1,
                     const float* __restrict__ W_ih2, const float* __restrict__ W_hh2,
                     const float* __restrict__ b_ih2, const float* __restrict__ b_hh2,
                     const float* __restrict__ W_lin, const float* __restrict__ b_lin,
                     float* __restrict__ out)
{
    const int tid  = threadIdx.x;
    const int wq   = tid >> 6;
    const int lane = tid & 63;
    const int u    = lane >> 4;        // K-block row / D row-group
    const int c    = lane & 15;        // MFMA col (B/D) and A-row
    const int s    = c & 3;            // sample within wave
    const int cg   = c >> 2;           // col-group == owned-unit offset
    const int b0   = (blockIdx.x * 4 + wq) * 4;

    const float L2E = 1.442695040888963f;
    const float sA[4] = {-L2E, -L2E, -2.0f * L2E, -L2E};
    const float blin = b_lin[0];

    // ---- static A fragments (chunk = gate, rows = units) + bias C ----
    v8h   A1[4], A2[4];
    f32x4 C1[4], C2[4];
    #pragma unroll
    for (int m = 0; m < 4; ++m) {
        #pragma unroll
        for (int e = 0; e < 8; ++e) {
            const int k = (e < 4) ? (4 * u + e) : (16 + 4 * u + (e - 4));
            float v1 = 0.0f, v2 = 0.0f;
            if (c < HID) {
                const int wr = m * HID + c;            // gate m, unit c
                if (k < HID)       { v1 = W_hh1[wr * HID + k]; v2 = W_ih2[wr * HID + k]; }
                else if (k == HID) { v1 = W_ih1[wr]; }                     // x slot
                else if (k >= 16 && k < 16 + HID) { v2 = W_hh2[wr * HID + (k - 16)]; }
            }
            float a2v = sA[m] * v2;
            if (c == 15 && m == 3 && k >= 16 && k < 16 + HID)
                a2v = W_lin[k - 16];                   // out-row (unscaled)
            A1[m][e] = (_Float16)(sA[m] * v1);         // NOTE: k>=16 -> exact 0
            A2[m][e] = (_Float16)a2v;
        }
        #pragma unroll
        for (int r = 0; r < 4; ++r) {                  // D row 4u+r = unit 4u+r, gate m
            const int U = 4 * u + r;
            float bv1 = 0.0f, bv2 = 0.0f;
            if (U < HID) {
                bv1 = sA[m] * (b_ih1[m * HID + U] + b_hh1[m * HID + U]);
                bv2 = sA[m] * (b_ih2[m * HID + U] + b_hh2[m * HID + U]);
            }
            if (u == 3 && m == 3 && r == 3) bv2 = blin;   // out-row bias
            C1[m][r] = bv1; C2[m][r] = bv2;
        }
    }

    const int   Uown = 4 * u + cg;                     // owned unit
    const float wl2  = (Uown < HID) ? W_lin[Uown] : 0.0f;

    const bool cgb0  = (cg & 1) != 0;
    const bool cgb1  = (cg & 2) != 0;
    const bool u3b   = (u == 3);
    const int  a32   = (lane ^ 32) << 2;

    int B0 = 0, B1 = 0;                                // h1/x (VALU tree, fresh)
    int B2s = 0, B3s = 0;                              // h2 stale (settled)
    int B2f = 0, B3f = 0;                              // h2 fresh (swizzle)
    float c1v = 0.0f, c2v = 0.0f;
    float oA = 0.0f, oB = 0.0f;

    // P_m = q_m[cg] (constant-index cndmask tree)
    auto gsel = [&](const f32x4& q0, const f32x4& q1, const f32x4& q2, const f32x4& q3,
                    float& g0, float& g1, float& g2, float& g3) {
        auto pick = [&](const f32x4& q) -> float {
            const float t0 = cgb0 ? q[1] : q[0];
            const float t1 = cgb0 ? q[3] : q[2];
            return cgb1 ? t1 : t0;
        };
        g0 = pick(q0); g1 = pick(q1); g2 = pick(q2); g3 = pick(q3);
    };

    // joint-rcp LSTM cell update (verified R16)
    auto acts = [&](float g0, float g1, float g2, float g3, float& cv) -> float {
        const float Ei = exp2_(g0);
        const float Ef = exp2_(g1);
        const float Eg = exp2_(g2);
        const float Eo = exp2_(g3);
        const float Di = 1.0f + Ei;
        const float Df = 1.0f + Ef;
        const float Dg = 1.0f + Eg;
        const float P  = Di * Dg;
        const float t  = __builtin_fmaf(-Eg, Df, Df);          // (1-Eg)*Df
        const float numer = __builtin_fmaf(cv, P, t);
        cv = numer * rcp_(P * Df);
        const float Y  = exp2_(cv * -2.885390081777927f);
        return (1.0f - Y) * rcp_((1.0f + Y) * (1.0f + Eo));
    };

    // slots: s_j = h of unit 4u+j (verified R15/R16 tree; VALU-only)
    auto slots = [&](float h, float& s0, float& s1, float& s2, float& s3) {
        const int hb = __float_as_int(h);
        const float r4  = __int_as_float(dppi<0x114>(hb) | dppi<0x10C>(hb)); // ror4
        const float r8  = __int_as_float(dppi<0x118>(hb) | dppi<0x108>(hb)); // ror8
        const float r12 = __int_as_float(dppi<0x11C>(hb) | dppi<0x104>(hb)); // ror12
        const float A0 = cgb0 ? r4  : h;
        const float A1 = cgb0 ? r12 : r8;
        const float A2 = cgb0 ? h   : r12;
        const float A3 = cgb0 ? r8  : r4;
        s0 = cgb1 ? A1 : A0;
        s1 = cgb1 ? A3 : A2;
        s2 = cgb1 ? A0 : A1;
        s3 = cgb1 ? A2 : A3;
    };

    // pack01: L1-critical, VALU-only (no lgkm)
    auto pack01 = [&](float h1n, float xv) {
        float s0, s1, s2, s3; slots(h1n, s0, s1, s2, s3);
        B0 = __builtin_bit_cast(int, pkrtz(s0, s1));
        B1 = __builtin_bit_cast(int, pkrtz(s2, u3b ? xv : s3));
    };
    // pack23: h2 (slack) via swizzle broadcast (verified R18) into fresh regs
    auto pack23 = [&](float h2n) {
        const int hb = __float_as_int(h2n);
        const float hr = __int_as_float(dppi<0x104>(hb));      // col+4, 0-fill
        const int p = __builtin_bit_cast(int, pkrtz(h2n, hr));
        B2f = swzi<0x0013>(p);                         // (i&0x13)|0  -> col s
        B3f = swzi<0x0113>(p);                         // (i&0x13)|8  -> col 8+s
    };

    auto stash = [&](auto SigC, float ov) {            // slot sig -> oA/oB at cg==sig&3
        constexpr int SIG = decltype(SigC)::v;
        const bool own = (cg == (SIG & 3));
        if constexpr (SIG < 4) oA = own ? ov : oA;
        else                   oB = own ? ov : oB;
    };

    const size_t xadr   = (size_t)(b0 + s) * TMAIN;
    const size_t outb_o = (size_t)(b0 + s) * OUTW;

    auto storeChunk = [&](int chIdx, int baseOff) {
        if (u3b) {
            out[outb_o + baseOff + (size_t)chIdx * 8 + cg]     = oA;
            out[outb_o + baseOff + (size_t)chIdx * 8 + 4 + cg] = oB;
        }
    };

    // out = sum over 16 unit-lanes of this sample (verified chain)
    auto outdot = [&](float h) -> float {
        float pv = wl2 * h;
        pv += swzf<0x101F>(pv);                        // xor 4  (cg bit0)
        pv += swzf<0x201F>(pv);                        // xor 8  (cg bit1)
        pv += swzf<0x401F>(pv);                        // xor 16 (u bit0)
        pv += bpermf(a32, pv);                         // xor 32 (u bit1)
        return pv + blin;
    };

    // pipelined iteration t: fresh B = {h1(t), x(t+1), h2(t-1)}
    // L1 (d) MFMAs FIRST with STALE B2s/B3s (A1 zeros there -> no lgkm dep);
    // e-MFMAs with fresh B2f/B3f (lgkm covered by d issue).
    auto iterP = [&](auto Sc, float xv2) {
        constexpr int S = decltype(Sc)::v;
        const v8h Bd = __builtin_bit_cast(v8h, (i32x4){B0, B1, B2s, B3s});
        f32x4 d0 = mfma16(A1[0], Bd, C1[0]);
        f32x4 d1 = mfma16(A1[1], Bd, C1[1]);
        f32x4 d2 = mfma16(A1[2], Bd, C1[2]);
        f32x4 d3 = mfma16(A1[3], Bd, C1[3]);
        const v8h Be = __builtin_bit_cast(v8h, (i32x4){B0, B1, B2f, B3f});
        f32x4 e0 = mfma16(A2[0], Be, C2[0]);
        f32x4 e1 = mfma16(A2[1], Be, C2[1]);
        f32x4 e2 = mfma16(A2[2], Be, C2[2]);
        f32x4 e3 = mfma16(A2[3], Be, C2[3]);

        // ---- L1 chain first (the recurrence) ----
        float P0, P1, P2, P3;
        gsel(d0, d1, d2, d3, P0, P1, P2, P3);
        const float h1n = acts(P0, P1, P2, P3, c1v);   // h1(t+1) (pad: exact 0)
        pack01(h1n, xv2);                              // VALU-only

        // ---- L2 chain (slack) ----
        stash(ic<(S + 7) & 7>{}, e3[3]);               // ov(t-1)
        float Q0, Q1, Q2, Q3;
        gsel(e0, e1, e2, e3, Q0, Q1, Q2, Q3);
        const float h2n = acts(Q0, Q1, Q2, Q3, c2v);   // h2(t)

        B2s = B2f; B3s = B3f;                          // retire fresh -> stale
        pack23(h2n);                                   // swizzles (slack)
    };

    // serial step (future): B = {h1(t-1), x(t)=ov(t-1), h2(t-1)}
    auto stepS = [&](auto Sc) {
        constexpr int S = decltype(Sc)::v;
        const v8h Bd = __builtin_bit_cast(v8h, (i32x4){B0, B1, B2s, B3s});
        f32x4 d0 = mfma16(A1[0], Bd, C1[0]);
        f32x4 d1 = mfma16(A1[1], Bd, C1[1]);
        f32x4 d2 = mfma16(A1[2], Bd, C1[2]);
        f32x4 d3 = mfma16(A1[3], Bd, C1[3]);
        float P0, P1, P2, P3;
        gsel(d0, d1, d2, d3, P0, P1, P2, P3);
        const float h1n = acts(P0, P1, P2, P3, c1v);
        pack01(h1n, 0.0f);                             // x patched after ov known

        const v8h Be = __builtin_bit_cast(v8h, (i32x4){B0, B1, B2f, B3f});
        f32x4 e0 = mfma16(A2[0], Be, C2[0]);
        f32x4 e1 = mfma16(A2[1], Be, C2[1]);
        f32x4 e2 = mfma16(A2[2], Be, C2[2]);
        f32x4 e3 = mfma16(A2[3], Be, C2[3]);
        float Q0, Q1, Q2, Q3;
        gsel(e0, e1, e2, e3, Q0, Q1, Q2, Q3);
        const float h2n = acts(Q0, Q1, Q2, Q3, c2v);

        const float ov = outdot(h2n);                  // ov(t)
        stash(ic<S>{}, ov);
        // patch x(t+1)=ov into B1.hi at u3
        const int xb = __builtin_bit_cast(int, pkrtz(0.0f, ov)) & 0xFFFF0000;
        B1 = u3b ? ((B1 & 0xFFFF) | xb) : B1;
        B2s = B2f; B3s = B3f;
        pack23(h2n);
    };

    // ---- prologue: h(-1)=0; h1(0); B(0) = {h1(0), x(1), 0} ----
    f32x4 xcA = *(const f32x4*)&input[xadr];
    f32x4 xcB = *(const f32x4*)&input[xadr + 4];
    {
        B0 = 0;
        B1 = u3b ? __builtin_bit_cast(int, pkrtz(0.0f, xcA[0])) : 0;  // x(0)
        const v8h Bv = __builtin_bit_cast(v8h, (i32x4){B0, B1, 0, 0});
        f32x4 d0 = mfma16(A1[0], Bv, C1[0]);
        f32x4 d1 = mfma16(A1[1], Bv, C1[1]);
        f32x4 d2 = mfma16(A1[2], Bv, C1[2]);
        f32x4 d3 = mfma16(A1[3], Bv, C1[3]);
        float P0, P1, P2, P3;
        gsel(d0, d1, d2, d3, P0, P1, P2, P3);
        const float h1n = acts(P0, P1, P2, P3, c1v);
        pack01(h1n, xcA[1]);                           // x(1)
        B2s = B3s = B2f = B3f = 0;                     // h2(-1) = 0
    }

    // ---- main: 127 full chunks of 8 pipelined iters (t = 0..1015) ----
    #pragma unroll 1
    for (int ch = 0; ch < 127; ++ch) {
        const f32x4 xnA = *(const f32x4*)&input[xadr + (size_t)(ch + 1) * 8];
        const f32x4 xnB = *(const f32x4*)&input[xadr + (size_t)(ch + 1) * 8 + 4];
        iterP(ic<0>{}, xel<2>(xcA, xcB));
        if (ch > 0) storeChunk(ch - 1, 0);
        iterP(ic<1>{}, xel<3>(xcA, xcB));
        iterP(ic<2>{}, xel<4>(xcA, xcB));
        iterP(ic<3>{}, xel<5>(xcA, xcB));
        iterP(ic<4>{}, xel<6>(xcA, xcB));
        iterP(ic<5>{}, xel<7>(xcA, xcB));
        iterP(ic<6>{}, xnA[0]);
        iterP(ic<7>{}, xnA[1]);
        xcA = xnA; xcB = xnB;
    }

    // ---- final chunk (t = 1016..1022) + L2-only epilogue (h2(1023)) ----
    {
        iterP(ic<0>{}, xel<2>(xcA, xcB));
        storeChunk(126, 0);
        iterP(ic<1>{}, xel<3>(xcA, xcB));
        iterP(ic<2>{}, xel<4>(xcA, xcB));
        iterP(ic<3>{}, xel<5>(xcA, xcB));
        iterP(ic<4>{}, xel<6>(xcA, xcB));
        iterP(ic<5>{}, xel<7>(xcA, xcB));
        iterP(ic<6>{}, 0.0f);                          // x(1024) patched below

        // epilogue: B(1023) = {h1(1023), -, h2(1022)}
        const v8h Be = __builtin_bit_cast(v8h, (i32x4){B0, B1, B2f, B3f});
        f32x4 e0 = mfma16(A2[0], Be, C2[0]);
        f32x4 e1 = mfma16(A2[1], Be, C2[1]);
        f32x4 e2 = mfma16(A2[2], Be, C2[2]);
        f32x4 e3 = mfma16(A2[3], Be, C2[3]);
        stash(ic<6>{}, e3[3]);                         // ov(1022)
        float Q0, Q1, Q2, Q3;
        gsel(e0, e1, e2, e3, Q0, Q1, Q2, Q3);
        const float h2n = acts(Q0, Q1, Q2, Q3, c2v);
        const float ov23 = outdot(h2n);                // ov(1023)
        stash(ic<7>{}, ov23);
        storeChunk(127, 0);
        // B(1024): keep B0,B1 (h1(1023)); x(1024)=ov(1023); fresh h2(1023)
        const int xb = __builtin_bit_cast(int, pkrtz(0.0f, ov23)) & 0xFFFF0000;
        B1 = u3b ? ((B1 & 0xFFFF) | xb) : B1;
        B2s = B2f; B3s = B3f;
        pack23(h2n);
    }

    // ---- future: 64 serial steps, x = previous out ----
    #pragma unroll 1
    for (int fc = 0; fc < FUT / 8; ++fc) {
        unroll_for<0, 8>([&](auto sc) { stepS(sc); });
        storeChunk(fc, TMAIN);
    }
}

extern "C" void kernel_launch(void* const* d_in, const int* in_sizes, int n_in,
                              void* d_out, int out_size, void* d_ws, size_t ws_size,
                              hipStream_t stream)
{
    const float* input = (const float*)d_in[0];
    const float* W_ih1 = (const float*)d_in[1];
    const float* W_hh1 = (const float*)d_in[2];
    const float* b_ih1 = (const float*)d_in[3];
    const float* b_hh1 = (const float*)d_in[4];
    const float* W_ih2 = (const float*)d_in[5];
    const float* W_hh2 = (const float*)d_in[6];
    const float* b_ih2 = (const float*)d_in[7];
    const float* b_hh2 = (const float*)d_in[8];
    const float* W_lin = (const float*)d_in[9];
    const float* b_lin = (const float*)d_in[10];
    // d_in[11] = future (=64), compiled in as FUT

    // 4096 batches / (4 per wave * 4 waves per block) = 256 blocks
    // (1024 waves = 1/SIMD; R17 showed thinner waves double total issue)
    lstm_seq_kernel<<<256, 256, 0, stream>>>(
        input, W_ih1, W_hh1, b_ih1, b_hh1,
        W_ih2, W_hh2, b_ih2, b_hh2, W_lin, b_lin,
        (float*)d_out);
}